// Round 11
// baseline (71.282 us; speedup 1.0000x reference)
//
#include <hip/hip_runtime.h>
#include <hip/hip_bf16.h>

#define NB 32
#define NN 1024
#define IND 128
#define HD 64

typedef float f32x4 __attribute__((ext_vector_type(4)));
typedef short bf16x8 __attribute__((ext_vector_type(8)));
typedef unsigned short ushortx4 __attribute__((ext_vector_type(4)));

union FragU { unsigned short us[8]; bf16x8 v; };

__device__ __forceinline__ unsigned short f2bf(float f) {
    union { float f; unsigned u; } x; x.f = f;
    unsigned r = x.u + 0x7FFFu + ((x.u >> 16) & 1u);  // RNE
    return (unsigned short)(r >> 16);
}
__device__ __forceinline__ float bf2f(unsigned short h) {
    union { unsigned u; float f; } x; x.u = ((unsigned)h) << 16; return x.f;
}

// async 16B global -> LDS (DMA, no VGPR dest; counted by vmcnt)
__device__ __forceinline__ void gl16(void* lds, const void* g) {
    __builtin_amdgcn_global_load_lds(
        (const __attribute__((address_space(1))) unsigned int*)g,
        (__attribute__((address_space(3))) unsigned int*)lds, 16, 0, 0);
}

// ---------------- kernel 0: weight prep (transpose + hi/lo bf16 split) ------
__global__ void prep_k(const float* __restrict__ W_h, const float* __restrict__ W_fc1,
                       const float* __restrict__ W_g1, const float* __restrict__ W_g2,
                       const float* __restrict__ b_g1, const float* __restrict__ b_g2,
                       unsigned short* __restrict__ WcT_hi, unsigned short* __restrict__ WcT_lo,
                       unsigned short* __restrict__ Wg1T_hi, unsigned short* __restrict__ Wg1T_lo,
                       unsigned short* __restrict__ Wg2T_hi, unsigned short* __restrict__ Wg2T_lo,
                       float* __restrict__ biasP1) {
    int t = blockIdx.x * blockDim.x + threadIdx.x;
    if (t < 16384) {
        int o = t >> 7, k = t & 127;
        float v = (o < 64) ? W_h[k * 64 + o] : W_fc1[k * 64 + (o - 64)];
        unsigned short hi = f2bf(v);
        WcT_hi[t] = hi; WcT_lo[t] = f2bf(v - bf2f(hi));
    } else if (t < 20480) {
        int r = t - 16384; int o = r >> 6, k = r & 63;
        float v = W_g1[k * 64 + o];
        unsigned short hi = f2bf(v);
        Wg1T_hi[r] = hi; Wg1T_lo[r] = f2bf(v - bf2f(hi));
    } else if (t < 24576) {
        int r = t - 20480; int o = r >> 6, k = r & 63;
        float v = W_g2[k * 64 + o];
        unsigned short hi = f2bf(v);
        Wg2T_hi[r] = hi; Wg2T_lo[r] = f2bf(v - bf2f(hi));
    } else if (t < 24640) {
        int j = t - 24576;
        biasP1[j] = b_g1[j] + b_g2[j];
    }
}

// ---------------- kernel 1: h (-> hF frag-major bf16), x_proj (f32), p1 -----
// (unchanged)
__global__ __launch_bounds__(64) void k1(
        const float* __restrict__ x,
        const unsigned short* __restrict__ WcT_hi, const unsigned short* __restrict__ WcT_lo,
        const unsigned short* __restrict__ Wg1T_hi, const unsigned short* __restrict__ Wg1T_lo,
        const float* __restrict__ b_h, const float* __restrict__ b_fc1,
        const float* __restrict__ biasP1,
        unsigned short* __restrict__ hF, float* __restrict__ xproj,
        float* __restrict__ p1) {
    __shared__ unsigned short lds_hi[16 * 64];
    __shared__ unsigned short lds_lo[16 * 64];

    const int lane = threadIdx.x;
    const int lr = lane & 15, lg = lane >> 4;
    const int blk = blockIdx.x;
    const int b = blk >> 6;
    const int n0 = (blk & 63) * 16;

    const float* xp = x + (size_t)(b * NN + n0 + lr) * IND;

    f32x4 xa[4][2];
#pragma unroll
    for (int ks = 0; ks < 4; ks++) {
        const f32x4* ap = (const f32x4*)(xp + 32 * ks + 8 * lg);
        xa[ks][0] = ap[0]; xa[ks][1] = ap[1];
    }

    f32x4 acc[8];
#pragma unroll
    for (int f = 0; f < 8; f++) acc[f] = (f32x4){0.f, 0.f, 0.f, 0.f};

#pragma unroll
    for (int ks = 0; ks < 4; ks++) {
        FragU ah, al;
#pragma unroll
        for (int i = 0; i < 4; i++) {
            unsigned short h0 = f2bf(xa[ks][0][i]); ah.us[i] = h0;     al.us[i]     = f2bf(xa[ks][0][i] - bf2f(h0));
            unsigned short h1 = f2bf(xa[ks][1][i]); ah.us[4 + i] = h1; al.us[4 + i] = f2bf(xa[ks][1][i] - bf2f(h1));
        }
#pragma unroll
        for (int f = 0; f < 8; f++) {
            int off = (16 * f + lr) * 128 + 32 * ks + 8 * lg;
            bf16x8 wh = *(const bf16x8*)(WcT_hi + off);
            bf16x8 wl = *(const bf16x8*)(WcT_lo + off);
            acc[f] = __builtin_amdgcn_mfma_f32_16x16x32_bf16(ah.v, wh, acc[f], 0, 0, 0);
            acc[f] = __builtin_amdgcn_mfma_f32_16x16x32_bf16(ah.v, wl, acc[f], 0, 0, 0);
            acc[f] = __builtin_amdgcn_mfma_f32_16x16x32_bf16(al.v, wh, acc[f], 0, 0, 0);
        }
    }

    const int mb = n0 + 4 * lg;
    const int tile = mb >> 5;
    const int lanepart = lr + 16 * ((mb >> 3) & 3);
    const int j0 = mb & 7;

#pragma unroll
    for (int f = 0; f < 4; f++) {
        int c = 16 * f + lr;
        float bh = b_h[c];
        ushortx4 hv;
#pragma unroll
        for (int r = 0; r < 4; r++) hv[r] = f2bf(acc[f][r] + bh);
        *(ushortx4*)(hF + (size_t)b * 65536 + (size_t)(tile * 4 + f) * 512 + lanepart * 8 + j0) = hv;
    }

#pragma unroll
    for (int f = 4; f < 8; f++) {
        int c = 16 * (f - 4) + lr;
        float bp = b_fc1[c];
#pragma unroll
        for (int r = 0; r < 4; r++) {
            float v = acc[f][r] + bp;
            int n = mb + r;
            xproj[(size_t)(b * NN + n) * 64 + c] = v;
            int ln = 4 * lg + r;
            int idx = ln * 64 + (((c >> 3) ^ (ln & 7)) << 3) + (c & 7);
            unsigned short hi = f2bf(v);
            lds_hi[idx] = hi;
            lds_lo[idx] = f2bf(v - bf2f(hi));
        }
    }
    __syncthreads();

    f32x4 accP[4];
#pragma unroll
    for (int f = 0; f < 4; f++) accP[f] = (f32x4){0.f, 0.f, 0.f, 0.f};
#pragma unroll
    for (int ks = 0; ks < 2; ks++) {
        int c0 = 32 * ks + 8 * lg;
        int idx = lr * 64 + (((c0 >> 3) ^ (lr & 7)) << 3);
        bf16x8 a_hi = *(const bf16x8*)(lds_hi + idx);
        bf16x8 a_lo = *(const bf16x8*)(lds_lo + idx);
#pragma unroll
        for (int f = 0; f < 4; f++) {
            int off = (16 * f + lr) * 64 + c0;
            bf16x8 b_hi = *(const bf16x8*)(Wg1T_hi + off);
            bf16x8 b_lo = *(const bf16x8*)(Wg1T_lo + off);
            accP[f] = __builtin_amdgcn_mfma_f32_16x16x32_bf16(a_hi, b_hi, accP[f], 0, 0, 0);
            accP[f] = __builtin_amdgcn_mfma_f32_16x16x32_bf16(a_hi, b_lo, accP[f], 0, 0, 0);
            accP[f] = __builtin_amdgcn_mfma_f32_16x16x32_bf16(a_lo, b_hi, accP[f], 0, 0, 0);
        }
    }
#pragma unroll
    for (int f = 0; f < 4; f++) {
        int c = 16 * f + lr;
        float bb = biasP1[c];
#pragma unroll
        for (int r = 0; r < 4; r++) {
            int n = mb + r;
            p1[(size_t)(b * NN + n) * 64 + c] = accP[f][r] + bb;
        }
    }
}

// ---------------- kernel 2: x_new = A@h, SEQUENTIAL staging; fused epilogue -
// grid 2048 x 256, 2 blocks/CU. Block = one 16-row strip = 64 KB CONTIGUOUS
// region of A, staged in strict address order (row 0's 4KB, row 1, ...) as
// ONE phase of 64 gl16 (64 KB in flight), then barrier, then barrier-free
// compute from LDS (full K) + hF reg-loads. Cross-block overlap: while this
// block computes, the CU's sibling block stages. XOR-granule swizzle via
// pre-swizzled DMA source; read with same XOR (<=2-way conflicts, free).
__global__ __launch_bounds__(256, 2) void k2(
        const float* __restrict__ A, const unsigned short* __restrict__ hF,
        const unsigned short* __restrict__ Wg2T_hi, const unsigned short* __restrict__ Wg2T_lo,
        const float* __restrict__ p1, const float* __restrict__ xproj,
        float* __restrict__ out) {
    __shared__ char smem[65536];   // A: 16 rows x 4 KB, granule-swizzled

    const int tid = threadIdx.x;
    const int w = tid >> 6, lane = tid & 63;
    const int lr = lane & 15, lg = lane >> 4;

    // XCD-bijective swizzle (2048 % 8 == 0): one sequential stream per XCD
    const int bid = blockIdx.x;
    const int wgid = (bid & 7) * 256 + (bid >> 3);
    const int b = wgid >> 6;
    const int strip = wgid & 63;

    // ---- STAGE phase: 64 KB contiguous, sequential order ----
    // wave w stages rows 4w..4w+3; row rl = 4 chunks of 1 KB in address order.
    // dest granule d = c*64+lane holds source granule d^rl (rl<16 -> low bits).
#pragma unroll
    for (int i = 0; i < 4; i++) {
        const int rl = w * 4 + i;
        const float* rowp = A + (size_t)(b * NN + strip * 16 + rl) * NN;
        char* ldsrow = smem + rl * 4096;
#pragma unroll
        for (int c = 0; c < 4; c++)
            gl16(ldsrow + c * 1024, rowp + c * 256 + ((lane ^ rl) << 2));
    }

    // hF frags for first 8 K-steps (independent; drained by the barrier)
    const unsigned short* hp = hF + (size_t)b * 65536 + w * 512 + lane * 8;
    bf16x8 hb[8];
#pragma unroll
    for (int ks = 0; ks < 8; ks++)
        hb[ks] = *(const bf16x8*)(hp + (size_t)ks * 2048);

    __syncthreads();   // vmcnt(0) drain: all A + hb resident

    // ---- COMPUTE phase: barrier-free, full K from LDS ----
    f32x4 acc = (f32x4){0.f, 0.f, 0.f, 0.f};
    const char* Abase = smem + lr * 4096;   // this lane's row

#define COMPUTE(KABS, KREG)                                                    \
    {                                                                          \
        int g0 = (KABS) * 8 + lg * 2;                                          \
        f32x4 a0 = *(const f32x4*)(Abase + ((g0 ^ lr) << 4));                  \
        f32x4 a1 = *(const f32x4*)(Abase + (((g0 + 1) ^ lr) << 4));            \
        FragU au;                                                              \
        _Pragma("unroll")                                                      \
        for (int ii = 0; ii < 4; ii++) {                                       \
            au.us[ii] = f2bf(a0[ii]); au.us[4 + ii] = f2bf(a1[ii]);            \
        }                                                                      \
        acc = __builtin_amdgcn_mfma_f32_16x16x32_bf16(au.v, hb[KREG], acc, 0, 0, 0); \
    }

#pragma unroll
    for (int t = 0; t < 4; t++) {
        COMPUTE(t * 8 + 0, 0) COMPUTE(t * 8 + 1, 1)
        COMPUTE(t * 8 + 2, 2) COMPUTE(t * 8 + 3, 3)
        if (t < 3) {
#pragma unroll
            for (int ks = 0; ks < 4; ks++)
                hb[ks] = *(const bf16x8*)(hp + (size_t)((t + 1) * 8 + ks) * 2048);
        }
        COMPUTE(t * 8 + 4, 4) COMPUTE(t * 8 + 5, 5)
        COMPUTE(t * 8 + 6, 6) COMPUTE(t * 8 + 7, 7)
        if (t < 3) {
#pragma unroll
            for (int ks = 4; ks < 8; ks++)
                hb[ks] = *(const bf16x8*)(hp + (size_t)((t + 1) * 8 + ks) * 2048);
        }
    }
#undef COMPUTE

    __syncthreads();   // all waves done reading A before smem reuse

    // ---- epilogue (r10-verified 16x64 form), reusing smem ----
    unsigned short* th = (unsigned short*)smem;
    unsigned short* tl = th + 1024;
    {
        int c = 16 * w + lr;
#pragma unroll
        for (int r = 0; r < 4; r++) {
            int row = 4 * lg + r;
            int idx = row * 64 + (((c >> 3) ^ (row & 7)) << 3) + (c & 7);
            float v = acc[r];
            unsigned short hi = f2bf(v);
            th[idx] = hi;
            tl[idx] = f2bf(v - bf2f(hi));
        }
    }
    __syncthreads();

    // g2 = x_new @ W_g2 (split precision); wave w computes col-frag f=w
    f32x4 accG = (f32x4){0.f, 0.f, 0.f, 0.f};
#pragma unroll
    for (int ksk = 0; ksk < 2; ksk++) {
        int c0k = 32 * ksk + 8 * lg;
        int idx = lr * 64 + (((c0k >> 3) ^ (lr & 7)) << 3);
        bf16x8 a_hi = *(const bf16x8*)(th + idx);
        bf16x8 a_lo = *(const bf16x8*)(tl + idx);
        int off = (16 * w + lr) * 64 + c0k;
        bf16x8 b_hi = *(const bf16x8*)(Wg2T_hi + off);
        bf16x8 b_lo = *(const bf16x8*)(Wg2T_lo + off);
        accG = __builtin_amdgcn_mfma_f32_16x16x32_bf16(a_hi, b_hi, accG, 0, 0, 0);
        accG = __builtin_amdgcn_mfma_f32_16x16x32_bf16(a_hi, b_lo, accG, 0, 0, 0);
        accG = __builtin_amdgcn_mfma_f32_16x16x32_bf16(a_lo, b_hi, accG, 0, 0, 0);
    }

    // fused epilogue: gate = sigmoid(p1 + g2); out = xnew*g + xproj*(1-g)
    {
        int c = 16 * w + lr;
#pragma unroll
        for (int r = 0; r < 4; r++) {
            int n = strip * 16 + 4 * lg + r;
            size_t g = (size_t)(b * NN + n) * 64 + c;
            float z = p1[g] + accG[r];
            float gate = 1.f / (1.f + __expf(-z));
            float xpv = xproj[g];
            out[g] = acc[r] * gate + xpv * (1.f - gate);
        }
    }
}

extern "C" void kernel_launch(void* const* d_in, const int* in_sizes, int n_in,
                              void* d_out, int out_size, void* d_ws, size_t ws_size,
                              hipStream_t stream) {
    const float* x     = (const float*)d_in[0];
    const float* A     = (const float*)d_in[1];
    const float* W_h   = (const float*)d_in[2];
    const float* b_h   = (const float*)d_in[3];
    const float* W_fc1 = (const float*)d_in[4];
    const float* b_fc1 = (const float*)d_in[5];
    const float* W_g1  = (const float*)d_in[6];
    const float* b_g1  = (const float*)d_in[7];
    const float* W_g2  = (const float*)d_in[8];
    const float* b_g2  = (const float*)d_in[9];
    float* out = (float*)d_out;

    char* ws = (char*)d_ws;
    unsigned short* WcT_hi  = (unsigned short*)(ws);            // 32 KB
    unsigned short* WcT_lo  = (unsigned short*)(ws + 32768);    // 32 KB
    unsigned short* Wg1T_hi = (unsigned short*)(ws + 65536);    // 8 KB
    unsigned short* Wg1T_lo = (unsigned short*)(ws + 73728);    // 8 KB
    unsigned short* Wg2T_hi = (unsigned short*)(ws + 81920);    // 8 KB
    unsigned short* Wg2T_lo = (unsigned short*)(ws + 90112);    // 8 KB
    float*          bP1     = (float*)(ws + 98304);             // 256 B
    unsigned short* hF      = (unsigned short*)(ws + 131072);                      // 4 MB
    float*          xprj    = (float*)(ws + 131072 + 4194304);                     // 8 MB
    float*          p1      = (float*)(ws + 131072 + 4194304 + 8388608);           // 8 MB

    prep_k<<<97, 256, 0, stream>>>(W_h, W_fc1, W_g1, W_g2, b_g1, b_g2,
                                   WcT_hi, WcT_lo, Wg1T_hi, Wg1T_lo, Wg2T_hi, Wg2T_lo, bP1);
    k1<<<2048, 64, 0, stream>>>(x, WcT_hi, WcT_lo, Wg1T_hi, Wg1T_lo, b_h, b_fc1, bP1,
                                hF, xprj, p1);
    k2<<<2048, 256, 0, stream>>>(A, hF, Wg2T_hi, Wg2T_lo, p1, xprj, out);
}

// Round 12
// 63.402 us; speedup vs baseline: 1.1243x; 1.1243x over previous
//
#include <hip/hip_runtime.h>
#include <hip/hip_bf16.h>

#define NB 32
#define NN 1024
#define IND 128
#define HD 64

typedef float f32x4 __attribute__((ext_vector_type(4)));
typedef short bf16x8 __attribute__((ext_vector_type(8)));
typedef unsigned short ushortx4 __attribute__((ext_vector_type(4)));

union FragU { unsigned short us[8]; bf16x8 v; };

__device__ __forceinline__ unsigned short f2bf(float f) {
    union { float f; unsigned u; } x; x.f = f;
    unsigned r = x.u + 0x7FFFu + ((x.u >> 16) & 1u);  // RNE
    return (unsigned short)(r >> 16);
}
__device__ __forceinline__ float bf2f(unsigned short h) {
    union { unsigned u; float f; } x; x.u = ((unsigned)h) << 16; return x.f;
}

// async 16B global -> LDS (DMA, no VGPR dest; counted by vmcnt)
__device__ __forceinline__ void gl16(void* lds, const void* g) {
    __builtin_amdgcn_global_load_lds(
        (const __attribute__((address_space(1))) unsigned int*)g,
        (__attribute__((address_space(3))) unsigned int*)lds, 16, 0, 0);
}

// ---------------- kernel 0: weight prep (transpose + hi/lo bf16 split) ------
__global__ void prep_k(const float* __restrict__ W_h, const float* __restrict__ W_fc1,
                       const float* __restrict__ W_g1, const float* __restrict__ W_g2,
                       const float* __restrict__ b_g1, const float* __restrict__ b_g2,
                       unsigned short* __restrict__ WcT_hi, unsigned short* __restrict__ WcT_lo,
                       unsigned short* __restrict__ Wg1T_hi, unsigned short* __restrict__ Wg1T_lo,
                       unsigned short* __restrict__ Wg2T_hi, unsigned short* __restrict__ Wg2T_lo,
                       float* __restrict__ biasP1) {
    int t = blockIdx.x * blockDim.x + threadIdx.x;
    if (t < 16384) {
        int o = t >> 7, k = t & 127;
        float v = (o < 64) ? W_h[k * 64 + o] : W_fc1[k * 64 + (o - 64)];
        unsigned short hi = f2bf(v);
        WcT_hi[t] = hi; WcT_lo[t] = f2bf(v - bf2f(hi));
    } else if (t < 20480) {
        int r = t - 16384; int o = r >> 6, k = r & 63;
        float v = W_g1[k * 64 + o];
        unsigned short hi = f2bf(v);
        Wg1T_hi[r] = hi; Wg1T_lo[r] = f2bf(v - bf2f(hi));
    } else if (t < 24576) {
        int r = t - 20480; int o = r >> 6, k = r & 63;
        float v = W_g2[k * 64 + o];
        unsigned short hi = f2bf(v);
        Wg2T_hi[r] = hi; Wg2T_lo[r] = f2bf(v - bf2f(hi));
    } else if (t < 24640) {
        int j = t - 24576;
        biasP1[j] = b_g1[j] + b_g2[j];
    }
}

// ---------------- kernel 1: h (-> hF frag-major bf16), x_proj (f32), p1 -----
// (unchanged)
__global__ __launch_bounds__(64) void k1(
        const float* __restrict__ x,
        const unsigned short* __restrict__ WcT_hi, const unsigned short* __restrict__ WcT_lo,
        const unsigned short* __restrict__ Wg1T_hi, const unsigned short* __restrict__ Wg1T_lo,
        const float* __restrict__ b_h, const float* __restrict__ b_fc1,
        const float* __restrict__ biasP1,
        unsigned short* __restrict__ hF, float* __restrict__ xproj,
        float* __restrict__ p1) {
    __shared__ unsigned short lds_hi[16 * 64];
    __shared__ unsigned short lds_lo[16 * 64];

    const int lane = threadIdx.x;
    const int lr = lane & 15, lg = lane >> 4;
    const int blk = blockIdx.x;
    const int b = blk >> 6;
    const int n0 = (blk & 63) * 16;

    const float* xp = x + (size_t)(b * NN + n0 + lr) * IND;

    f32x4 xa[4][2];
#pragma unroll
    for (int ks = 0; ks < 4; ks++) {
        const f32x4* ap = (const f32x4*)(xp + 32 * ks + 8 * lg);
        xa[ks][0] = ap[0]; xa[ks][1] = ap[1];
    }

    f32x4 acc[8];
#pragma unroll
    for (int f = 0; f < 8; f++) acc[f] = (f32x4){0.f, 0.f, 0.f, 0.f};

#pragma unroll
    for (int ks = 0; ks < 4; ks++) {
        FragU ah, al;
#pragma unroll
        for (int i = 0; i < 4; i++) {
            unsigned short h0 = f2bf(xa[ks][0][i]); ah.us[i] = h0;     al.us[i]     = f2bf(xa[ks][0][i] - bf2f(h0));
            unsigned short h1 = f2bf(xa[ks][1][i]); ah.us[4 + i] = h1; al.us[4 + i] = f2bf(xa[ks][1][i] - bf2f(h1));
        }
#pragma unroll
        for (int f = 0; f < 8; f++) {
            int off = (16 * f + lr) * 128 + 32 * ks + 8 * lg;
            bf16x8 wh = *(const bf16x8*)(WcT_hi + off);
            bf16x8 wl = *(const bf16x8*)(WcT_lo + off);
            acc[f] = __builtin_amdgcn_mfma_f32_16x16x32_bf16(ah.v, wh, acc[f], 0, 0, 0);
            acc[f] = __builtin_amdgcn_mfma_f32_16x16x32_bf16(ah.v, wl, acc[f], 0, 0, 0);
            acc[f] = __builtin_amdgcn_mfma_f32_16x16x32_bf16(al.v, wh, acc[f], 0, 0, 0);
        }
    }

    const int mb = n0 + 4 * lg;
    const int tile = mb >> 5;
    const int lanepart = lr + 16 * ((mb >> 3) & 3);
    const int j0 = mb & 7;

#pragma unroll
    for (int f = 0; f < 4; f++) {
        int c = 16 * f + lr;
        float bh = b_h[c];
        ushortx4 hv;
#pragma unroll
        for (int r = 0; r < 4; r++) hv[r] = f2bf(acc[f][r] + bh);
        *(ushortx4*)(hF + (size_t)b * 65536 + (size_t)(tile * 4 + f) * 512 + lanepart * 8 + j0) = hv;
    }

#pragma unroll
    for (int f = 4; f < 8; f++) {
        int c = 16 * (f - 4) + lr;
        float bp = b_fc1[c];
#pragma unroll
        for (int r = 0; r < 4; r++) {
            float v = acc[f][r] + bp;
            int n = mb + r;
            xproj[(size_t)(b * NN + n) * 64 + c] = v;
            int ln = 4 * lg + r;
            int idx = ln * 64 + (((c >> 3) ^ (ln & 7)) << 3) + (c & 7);
            unsigned short hi = f2bf(v);
            lds_hi[idx] = hi;
            lds_lo[idx] = f2bf(v - bf2f(hi));
        }
    }
    __syncthreads();

    f32x4 accP[4];
#pragma unroll
    for (int f = 0; f < 4; f++) accP[f] = (f32x4){0.f, 0.f, 0.f, 0.f};
#pragma unroll
    for (int ks = 0; ks < 2; ks++) {
        int c0 = 32 * ks + 8 * lg;
        int idx = lr * 64 + (((c0 >> 3) ^ (lr & 7)) << 3);
        bf16x8 a_hi = *(const bf16x8*)(lds_hi + idx);
        bf16x8 a_lo = *(const bf16x8*)(lds_lo + idx);
#pragma unroll
        for (int f = 0; f < 4; f++) {
            int off = (16 * f + lr) * 64 + c0;
            bf16x8 b_hi = *(const bf16x8*)(Wg1T_hi + off);
            bf16x8 b_lo = *(const bf16x8*)(Wg1T_lo + off);
            accP[f] = __builtin_amdgcn_mfma_f32_16x16x32_bf16(a_hi, b_hi, accP[f], 0, 0, 0);
            accP[f] = __builtin_amdgcn_mfma_f32_16x16x32_bf16(a_hi, b_lo, accP[f], 0, 0, 0);
            accP[f] = __builtin_amdgcn_mfma_f32_16x16x32_bf16(a_lo, b_hi, accP[f], 0, 0, 0);
        }
    }
#pragma unroll
    for (int f = 0; f < 4; f++) {
        int c = 16 * f + lr;
        float bb = biasP1[c];
#pragma unroll
        for (int r = 0; r < 4; r++) {
            int n = mb + r;
            p1[(size_t)(b * NN + n) * 64 + c] = accP[f][r] + bb;
        }
    }
}

// ---------------- kernel 2: x_new = A@h, staged DMA, 2 strips/block ---------
// grid 1024 x 256, __launch_bounds__(256,4): exactly 4 blocks/CU, ONE cohort,
// all blocks co-resident. Block = 2 consecutive 16-row strips (128 KB
// contiguous A), processed sequentially with r10's per-tile staged structure
// (BK=256, 2 x 16 KB A slots, double-buffered, pre-swizzled DMA source).
// Cross-strip prefetch: during strip-0's last tile, stage strip-1's tile 0
// (slot parity continues) + preload its hF frags, so the inter-strip
// epilogue hides the staging latency. Epilogue uses a dedicated 4 KB LDS
// region (no collision with in-flight DMA). Total LDS 36 KB.
__global__ __launch_bounds__(256, 4) void k2(
        const float* __restrict__ A, const unsigned short* __restrict__ hF,
        const unsigned short* __restrict__ Wg2T_hi, const unsigned short* __restrict__ Wg2T_lo,
        const float* __restrict__ p1, const float* __restrict__ xproj,
        float* __restrict__ out) {
    __shared__ char smem[36864];   // A slots @0,@16384; epilogue @32768

    const int tid = threadIdx.x;
    const int w = tid >> 6, lane = tid & 63;
    const int lr = lane & 15, lg = lane >> 4;

    // XCD-bijective swizzle (1024 % 8 == 0)
    const int bid = blockIdx.x;
    const int wgid = (bid & 7) * 128 + (bid >> 3);
    const int b = wgid >> 5;
    const int blkst = wgid & 31;          // 32 double-strips per batch

    // staging sources for strip 0; strip 1 = +16 rows = +16384 floats
    const float* aS[4];
#pragma unroll
    for (int i = 0; i < 4; i++) {
        int rl = w * 4 + i;
        aS[i] = A + (size_t)(b * NN + blkst * 32 + rl) * NN + ((lane ^ rl) << 2);
    }
    const unsigned short* hp = hF + (size_t)b * 65536 + w * 512 + lane * 8;

    bf16x8 hb[8];

    // prologue: stage strip0/tile0 -> slot0; load its hF frags
#pragma unroll
    for (int i = 0; i < 4; i++)
        gl16(smem + (w * 4 + i) * 1024, aS[i]);
#pragma unroll
    for (int ks = 0; ks < 8; ks++)
        hb[ks] = *(const bf16x8*)(hp + (size_t)ks * 2048);
    __syncthreads();

#define COMPUTE(ks, Abase)                                                     \
    {                                                                          \
        int g0 = (ks) * 8 + lg * 2;                                            \
        f32x4 a0 = *(const f32x4*)((Abase) + ((g0 ^ lr) << 4));                \
        f32x4 a1 = *(const f32x4*)((Abase) + (((g0 + 1) ^ lr) << 4));          \
        FragU au;                                                              \
        _Pragma("unroll")                                                      \
        for (int ii = 0; ii < 4; ii++) {                                       \
            au.us[ii] = f2bf(a0[ii]); au.us[4 + ii] = f2bf(a1[ii]);            \
        }                                                                      \
        acc = __builtin_amdgcn_mfma_f32_16x16x32_bf16(au.v, hb[ks], acc, 0, 0, 0); \
    }

#pragma unroll
    for (int s = 0; s < 2; s++) {
        f32x4 acc = (f32x4){0.f, 0.f, 0.f, 0.f};

#pragma unroll
        for (int t = 0; t < 4; t++) {
            const char* Abase = smem + (t & 1) * 16384 + lr * 1024;
            const bool last = (s == 1) && (t == 3);
            // stage the NEXT tile in the global sequence (slot parity continues
            // across the strip boundary since 4 tiles/strip is even)
            if (!last) {
                const size_t soff = (t < 3) ? ((size_t)s * 16384 + (t + 1) * 256)
                                            : ((size_t)(s + 1) * 16384);
#pragma unroll
                for (int i = 0; i < 4; i++)
                    gl16(smem + ((t + 1) & 1) * 16384 + (w * 4 + i) * 1024,
                         aS[i] + soff);
            }
            const int tn = (t < 3) ? (t + 1) : 0;   // next tile's hF tile index

            COMPUTE(0, Abase) COMPUTE(1, Abase) COMPUTE(2, Abase) COMPUTE(3, Abase)
            if (!last) {
#pragma unroll
                for (int ks = 0; ks < 4; ks++)
                    hb[ks] = *(const bf16x8*)(hp + (size_t)(tn * 8 + ks) * 2048);
            }
            COMPUTE(4, Abase) COMPUTE(5, Abase) COMPUTE(6, Abase) COMPUTE(7, Abase)
            if (!last) {
#pragma unroll
                for (int ks = 4; ks < 8; ks++)
                    hb[ks] = *(const bf16x8*)(hp + (size_t)(tn * 8 + ks) * 2048);
            }
            __syncthreads();   // drains this tile's reads + next tile's stage
        }

        // ---- epilogue for strip s (dedicated LDS region @32768) ----
        unsigned short* th = (unsigned short*)(smem + 32768);
        unsigned short* tl = th + 1024;
        {
            int c = 16 * w + lr;
#pragma unroll
            for (int r = 0; r < 4; r++) {
                int row = 4 * lg + r;
                int idx = row * 64 + (((c >> 3) ^ (row & 7)) << 3) + (c & 7);
                float v = acc[r];
                unsigned short hi = f2bf(v);
                th[idx] = hi;
                tl[idx] = f2bf(v - bf2f(hi));
            }
        }
        __syncthreads();

        // g2 = x_new @ W_g2 (split precision); wave w computes col-frag f=w
        f32x4 accG = (f32x4){0.f, 0.f, 0.f, 0.f};
#pragma unroll
        for (int ksk = 0; ksk < 2; ksk++) {
            int c0k = 32 * ksk + 8 * lg;
            int idx = lr * 64 + (((c0k >> 3) ^ (lr & 7)) << 3);
            bf16x8 a_hi = *(const bf16x8*)(th + idx);
            bf16x8 a_lo = *(const bf16x8*)(tl + idx);
            int off = (16 * w + lr) * 64 + c0k;
            bf16x8 b_hi = *(const bf16x8*)(Wg2T_hi + off);
            bf16x8 b_lo = *(const bf16x8*)(Wg2T_lo + off);
            accG = __builtin_amdgcn_mfma_f32_16x16x32_bf16(a_hi, b_hi, accG, 0, 0, 0);
            accG = __builtin_amdgcn_mfma_f32_16x16x32_bf16(a_hi, b_lo, accG, 0, 0, 0);
            accG = __builtin_amdgcn_mfma_f32_16x16x32_bf16(a_lo, b_hi, accG, 0, 0, 0);
        }

        // gate = sigmoid(p1 + g2); out = xnew*g + xproj*(1-g)
        {
            int c = 16 * w + lr;
#pragma unroll
            for (int r = 0; r < 4; r++) {
                int n = (blkst * 2 + s) * 16 + 4 * lg + r;
                size_t g = (size_t)(b * NN + n) * 64 + c;
                float z = p1[g] + accG[r];
                float gate = 1.f / (1.f + __expf(-z));
                float xpv = xproj[g];
                out[g] = acc[r] * gate + xpv * (1.f - gate);
            }
        }
        __syncthreads();   // epilogue LDS reads done before next strip reuses
    }
#undef COMPUTE
}

extern "C" void kernel_launch(void* const* d_in, const int* in_sizes, int n_in,
                              void* d_out, int out_size, void* d_ws, size_t ws_size,
                              hipStream_t stream) {
    const float* x     = (const float*)d_in[0];
    const float* A     = (const float*)d_in[1];
    const float* W_h   = (const float*)d_in[2];
    const float* b_h   = (const float*)d_in[3];
    const float* W_fc1 = (const float*)d_in[4];
    const float* b_fc1 = (const float*)d_in[5];
    const float* W_g1  = (const float*)d_in[6];
    const float* b_g1  = (const float*)d_in[7];
    const float* W_g2  = (const float*)d_in[8];
    const float* b_g2  = (const float*)d_in[9];
    float* out = (float*)d_out;

    char* ws = (char*)d_ws;
    unsigned short* WcT_hi  = (unsigned short*)(ws);            // 32 KB
    unsigned short* WcT_lo  = (unsigned short*)(ws + 32768);    // 32 KB
    unsigned short* Wg1T_hi = (unsigned short*)(ws + 65536);    // 8 KB
    unsigned short* Wg1T_lo = (unsigned short*)(ws + 73728);    // 8 KB
    unsigned short* Wg2T_hi = (unsigned short*)(ws + 81920);    // 8 KB
    unsigned short* Wg2T_lo = (unsigned short*)(ws + 90112);    // 8 KB
    float*          bP1     = (float*)(ws + 98304);             // 256 B
    unsigned short* hF      = (unsigned short*)(ws + 131072);                      // 4 MB
    float*          xprj    = (float*)(ws + 131072 + 4194304);                     // 8 MB
    float*          p1      = (float*)(ws + 131072 + 4194304 + 8388608);           // 8 MB

    prep_k<<<97, 256, 0, stream>>>(W_h, W_fc1, W_g1, W_g2, b_g1, b_g2,
                                   WcT_hi, WcT_lo, Wg1T_hi, Wg1T_lo, Wg2T_hi, Wg2T_lo, bP1);
    k1<<<2048, 64, 0, stream>>>(x, WcT_hi, WcT_lo, Wg1T_hi, Wg1T_lo, b_h, b_fc1, bP1,
                                hF, xprj, p1);
    k2<<<1024, 256, 0, stream>>>(A, hF, Wg2T_hi, Wg2T_lo, p1, xprj, out);
}

// Round 13
// 63.170 us; speedup vs baseline: 1.1284x; 1.0037x over previous
//
#include <hip/hip_runtime.h>
#include <hip/hip_bf16.h>

#define NB 32
#define NN 1024
#define IND 128
#define HD 64

typedef float f32x4 __attribute__((ext_vector_type(4)));
typedef short bf16x8 __attribute__((ext_vector_type(8)));
typedef unsigned short ushortx4 __attribute__((ext_vector_type(4)));

union FragU { unsigned short us[8]; unsigned int u32[4]; bf16x8 v; };

__device__ __forceinline__ unsigned short f2bf(float f) {
    union { float f; unsigned u; } x; x.f = f;
    unsigned r = x.u + 0x7FFFu + ((x.u >> 16) & 1u);  // RNE
    return (unsigned short)(r >> 16);
}
__device__ __forceinline__ float bf2f(unsigned short h) {
    union { unsigned u; float f; } x; x.u = ((unsigned)h) << 16; return x.f;
}
// packed HW convert: dst = {bf16(lo), bf16(hi)} in one VALU op
__device__ __forceinline__ unsigned int cvtpk(float lo, float hi) {
    unsigned int r;
    asm("v_cvt_pk_bf16_f32 %0, %1, %2" : "=v"(r) : "v"(lo), "v"(hi));
    return r;
}

// async 16B global -> LDS (DMA, no VGPR dest; counted by vmcnt)
__device__ __forceinline__ void gl16(void* lds, const void* g) {
    __builtin_amdgcn_global_load_lds(
        (const __attribute__((address_space(1))) unsigned int*)g,
        (__attribute__((address_space(3))) unsigned int*)lds, 16, 0, 0);
}

// ---------------- kernel 0: weight prep (transpose + hi/lo bf16 split) ------
__global__ void prep_k(const float* __restrict__ W_h, const float* __restrict__ W_fc1,
                       const float* __restrict__ W_g1, const float* __restrict__ W_g2,
                       const float* __restrict__ b_g1, const float* __restrict__ b_g2,
                       unsigned short* __restrict__ WcT_hi, unsigned short* __restrict__ WcT_lo,
                       unsigned short* __restrict__ Wg1T_hi, unsigned short* __restrict__ Wg1T_lo,
                       unsigned short* __restrict__ Wg2T_hi, unsigned short* __restrict__ Wg2T_lo,
                       float* __restrict__ biasP1) {
    int t = blockIdx.x * blockDim.x + threadIdx.x;
    if (t < 16384) {
        int o = t >> 7, k = t & 127;
        float v = (o < 64) ? W_h[k * 64 + o] : W_fc1[k * 64 + (o - 64)];
        unsigned short hi = f2bf(v);
        WcT_hi[t] = hi; WcT_lo[t] = f2bf(v - bf2f(hi));
    } else if (t < 20480) {
        int r = t - 16384; int o = r >> 6, k = r & 63;
        float v = W_g1[k * 64 + o];
        unsigned short hi = f2bf(v);
        Wg1T_hi[r] = hi; Wg1T_lo[r] = f2bf(v - bf2f(hi));
    } else if (t < 24576) {
        int r = t - 20480; int o = r >> 6, k = r & 63;
        float v = W_g2[k * 64 + o];
        unsigned short hi = f2bf(v);
        Wg2T_hi[r] = hi; Wg2T_lo[r] = f2bf(v - bf2f(hi));
    } else if (t < 24640) {
        int j = t - 24576;
        biasP1[j] = b_g1[j] + b_g2[j];
    }
}

// ---------------- kernel 1: h (-> hF frag-major bf16), x_proj (f32), p1 -----
// (unchanged)
__global__ __launch_bounds__(64) void k1(
        const float* __restrict__ x,
        const unsigned short* __restrict__ WcT_hi, const unsigned short* __restrict__ WcT_lo,
        const unsigned short* __restrict__ Wg1T_hi, const unsigned short* __restrict__ Wg1T_lo,
        const float* __restrict__ b_h, const float* __restrict__ b_fc1,
        const float* __restrict__ biasP1,
        unsigned short* __restrict__ hF, float* __restrict__ xproj,
        float* __restrict__ p1) {
    __shared__ unsigned short lds_hi[16 * 64];
    __shared__ unsigned short lds_lo[16 * 64];

    const int lane = threadIdx.x;
    const int lr = lane & 15, lg = lane >> 4;
    const int blk = blockIdx.x;
    const int b = blk >> 6;
    const int n0 = (blk & 63) * 16;

    const float* xp = x + (size_t)(b * NN + n0 + lr) * IND;

    f32x4 xa[4][2];
#pragma unroll
    for (int ks = 0; ks < 4; ks++) {
        const f32x4* ap = (const f32x4*)(xp + 32 * ks + 8 * lg);
        xa[ks][0] = ap[0]; xa[ks][1] = ap[1];
    }

    f32x4 acc[8];
#pragma unroll
    for (int f = 0; f < 8; f++) acc[f] = (f32x4){0.f, 0.f, 0.f, 0.f};

#pragma unroll
    for (int ks = 0; ks < 4; ks++) {
        FragU ah, al;
#pragma unroll
        for (int i = 0; i < 4; i++) {
            unsigned short h0 = f2bf(xa[ks][0][i]); ah.us[i] = h0;     al.us[i]     = f2bf(xa[ks][0][i] - bf2f(h0));
            unsigned short h1 = f2bf(xa[ks][1][i]); ah.us[4 + i] = h1; al.us[4 + i] = f2bf(xa[ks][1][i] - bf2f(h1));
        }
#pragma unroll
        for (int f = 0; f < 8; f++) {
            int off = (16 * f + lr) * 128 + 32 * ks + 8 * lg;
            bf16x8 wh = *(const bf16x8*)(WcT_hi + off);
            bf16x8 wl = *(const bf16x8*)(WcT_lo + off);
            acc[f] = __builtin_amdgcn_mfma_f32_16x16x32_bf16(ah.v, wh, acc[f], 0, 0, 0);
            acc[f] = __builtin_amdgcn_mfma_f32_16x16x32_bf16(ah.v, wl, acc[f], 0, 0, 0);
            acc[f] = __builtin_amdgcn_mfma_f32_16x16x32_bf16(al.v, wh, acc[f], 0, 0, 0);
        }
    }

    const int mb = n0 + 4 * lg;
    const int tile = mb >> 5;
    const int lanepart = lr + 16 * ((mb >> 3) & 3);
    const int j0 = mb & 7;

#pragma unroll
    for (int f = 0; f < 4; f++) {
        int c = 16 * f + lr;
        float bh = b_h[c];
        ushortx4 hv;
#pragma unroll
        for (int r = 0; r < 4; r++) hv[r] = f2bf(acc[f][r] + bh);
        *(ushortx4*)(hF + (size_t)b * 65536 + (size_t)(tile * 4 + f) * 512 + lanepart * 8 + j0) = hv;
    }

#pragma unroll
    for (int f = 4; f < 8; f++) {
        int c = 16 * (f - 4) + lr;
        float bp = b_fc1[c];
#pragma unroll
        for (int r = 0; r < 4; r++) {
            float v = acc[f][r] + bp;
            int n = mb + r;
            xproj[(size_t)(b * NN + n) * 64 + c] = v;
            int ln = 4 * lg + r;
            int idx = ln * 64 + (((c >> 3) ^ (ln & 7)) << 3) + (c & 7);
            unsigned short hi = f2bf(v);
            lds_hi[idx] = hi;
            lds_lo[idx] = f2bf(v - bf2f(hi));
        }
    }
    __syncthreads();

    f32x4 accP[4];
#pragma unroll
    for (int f = 0; f < 4; f++) accP[f] = (f32x4){0.f, 0.f, 0.f, 0.f};
#pragma unroll
    for (int ks = 0; ks < 2; ks++) {
        int c0 = 32 * ks + 8 * lg;
        int idx = lr * 64 + (((c0 >> 3) ^ (lr & 7)) << 3);
        bf16x8 a_hi = *(const bf16x8*)(lds_hi + idx);
        bf16x8 a_lo = *(const bf16x8*)(lds_lo + idx);
#pragma unroll
        for (int f = 0; f < 4; f++) {
            int off = (16 * f + lr) * 64 + c0;
            bf16x8 b_hi = *(const bf16x8*)(Wg1T_hi + off);
            bf16x8 b_lo = *(const bf16x8*)(Wg1T_lo + off);
            accP[f] = __builtin_amdgcn_mfma_f32_16x16x32_bf16(a_hi, b_hi, accP[f], 0, 0, 0);
            accP[f] = __builtin_amdgcn_mfma_f32_16x16x32_bf16(a_hi, b_lo, accP[f], 0, 0, 0);
            accP[f] = __builtin_amdgcn_mfma_f32_16x16x32_bf16(a_lo, b_hi, accP[f], 0, 0, 0);
        }
    }
#pragma unroll
    for (int f = 0; f < 4; f++) {
        int c = 16 * f + lr;
        float bb = biasP1[c];
#pragma unroll
        for (int r = 0; r < 4; r++) {
            int n = mb + r;
            p1[(size_t)(b * NN + n) * 64 + c] = accP[f][r] + bb;
        }
    }
}

// ---------------- kernel 2: x_new = A@h, staged DMA + cvt_pk; fused epilogue
// r12 chassis (1024 blocks x 256, 4/CU, 2 strips/block, BK=256, double-buffer,
// pre-swizzled DMA source) with:
//  * A-convert via v_cvt_pk_bf16_f32 (4 ops/frag instead of ~32)
//  * epilogue p1/xproj prefetched into regs before the final drain barrier
__global__ __launch_bounds__(256, 4) void k2(
        const float* __restrict__ A, const unsigned short* __restrict__ hF,
        const unsigned short* __restrict__ Wg2T_hi, const unsigned short* __restrict__ Wg2T_lo,
        const float* __restrict__ p1, const float* __restrict__ xproj,
        float* __restrict__ out) {
    __shared__ char smem[36864];   // A slots @0,@16384; epilogue @32768

    const int tid = threadIdx.x;
    const int w = tid >> 6, lane = tid & 63;
    const int lr = lane & 15, lg = lane >> 4;

    // XCD-bijective swizzle (1024 % 8 == 0)
    const int bid = blockIdx.x;
    const int wgid = (bid & 7) * 128 + (bid >> 3);
    const int b = wgid >> 5;
    const int blkst = wgid & 31;          // 32 double-strips per batch

    const float* aS[4];
#pragma unroll
    for (int i = 0; i < 4; i++) {
        int rl = w * 4 + i;
        aS[i] = A + (size_t)(b * NN + blkst * 32 + rl) * NN + ((lane ^ rl) << 2);
    }
    const unsigned short* hp = hF + (size_t)b * 65536 + w * 512 + lane * 8;

    bf16x8 hb[8];

    // prologue: stage strip0/tile0 -> slot0; load its hF frags
#pragma unroll
    for (int i = 0; i < 4; i++)
        gl16(smem + (w * 4 + i) * 1024, aS[i]);
#pragma unroll
    for (int ks = 0; ks < 8; ks++)
        hb[ks] = *(const bf16x8*)(hp + (size_t)ks * 2048);
    __syncthreads();

#define COMPUTE(ks, Abase)                                                     \
    {                                                                          \
        int g0 = (ks) * 8 + lg * 2;                                            \
        f32x4 a0 = *(const f32x4*)((Abase) + ((g0 ^ lr) << 4));                \
        f32x4 a1 = *(const f32x4*)((Abase) + (((g0 + 1) ^ lr) << 4));          \
        FragU au;                                                              \
        au.u32[0] = cvtpk(a0[0], a0[1]); au.u32[1] = cvtpk(a0[2], a0[3]);      \
        au.u32[2] = cvtpk(a1[0], a1[1]); au.u32[3] = cvtpk(a1[2], a1[3]);      \
        acc = __builtin_amdgcn_mfma_f32_16x16x32_bf16(au.v, hb[ks], acc, 0, 0, 0); \
    }

#pragma unroll
    for (int s = 0; s < 2; s++) {
        f32x4 acc = (f32x4){0.f, 0.f, 0.f, 0.f};
        f32x4 pv, xv;   // epilogue prefetch regs

#pragma unroll
        for (int t = 0; t < 4; t++) {
            const char* Abase = smem + (t & 1) * 16384 + lr * 1024;
            const bool last = (s == 1) && (t == 3);
            if (!last) {
                const size_t soff = (t < 3) ? ((size_t)s * 16384 + (t + 1) * 256)
                                            : ((size_t)(s + 1) * 16384);
#pragma unroll
                for (int i = 0; i < 4; i++)
                    gl16(smem + ((t + 1) & 1) * 16384 + (w * 4 + i) * 1024,
                         aS[i] + soff);
            }
            const int tn = (t < 3) ? (t + 1) : 0;

            COMPUTE(0, Abase) COMPUTE(1, Abase) COMPUTE(2, Abase) COMPUTE(3, Abase)
            if (!last) {
#pragma unroll
                for (int ks = 0; ks < 4; ks++)
                    hb[ks] = *(const bf16x8*)(hp + (size_t)(tn * 8 + ks) * 2048);
            }
            COMPUTE(4, Abase) COMPUTE(5, Abase) COMPUTE(6, Abase) COMPUTE(7, Abase)
            if (!last) {
#pragma unroll
                for (int ks = 4; ks < 8; ks++)
                    hb[ks] = *(const bf16x8*)(hp + (size_t)(tn * 8 + ks) * 2048);
            }
            if (t == 3) {
                // prefetch this strip's epilogue inputs before the drain
                const int c = 16 * w + lr;
                const int nbase = (blkst * 2 + s) * 16 + 4 * lg;
                const float* pp = p1    + (size_t)(b * NN + nbase) * 64 + c;
                const float* xp = xproj + (size_t)(b * NN + nbase) * 64 + c;
#pragma unroll
                for (int r = 0; r < 4; r++) { pv[r] = pp[r * 64]; xv[r] = xp[r * 64]; }
            }
            __syncthreads();   // drains this tile's reads + next tile's stage
        }

        // ---- epilogue for strip s (dedicated LDS region @32768) ----
        unsigned short* th = (unsigned short*)(smem + 32768);
        unsigned short* tl = th + 1024;
        {
            int c = 16 * w + lr;
#pragma unroll
            for (int r = 0; r < 4; r++) {
                int row = 4 * lg + r;
                int idx = row * 64 + (((c >> 3) ^ (row & 7)) << 3) + (c & 7);
                float v = acc[r];
                unsigned short hi = f2bf(v);
                th[idx] = hi;
                tl[idx] = f2bf(v - bf2f(hi));
            }
        }
        __syncthreads();

        f32x4 accG = (f32x4){0.f, 0.f, 0.f, 0.f};
#pragma unroll
        for (int ksk = 0; ksk < 2; ksk++) {
            int c0k = 32 * ksk + 8 * lg;
            int idx = lr * 64 + (((c0k >> 3) ^ (lr & 7)) << 3);
            bf16x8 a_hi = *(const bf16x8*)(th + idx);
            bf16x8 a_lo = *(const bf16x8*)(tl + idx);
            int off = (16 * w + lr) * 64 + c0k;
            bf16x8 b_hi = *(const bf16x8*)(Wg2T_hi + off);
            bf16x8 b_lo = *(const bf16x8*)(Wg2T_lo + off);
            accG = __builtin_amdgcn_mfma_f32_16x16x32_bf16(a_hi, b_hi, accG, 0, 0, 0);
            accG = __builtin_amdgcn_mfma_f32_16x16x32_bf16(a_hi, b_lo, accG, 0, 0, 0);
            accG = __builtin_amdgcn_mfma_f32_16x16x32_bf16(a_lo, b_hi, accG, 0, 0, 0);
        }

        {
            int c = 16 * w + lr;
#pragma unroll
            for (int r = 0; r < 4; r++) {
                int n = (blkst * 2 + s) * 16 + 4 * lg + r;
                size_t g = (size_t)(b * NN + n) * 64 + c;
                float z = pv[r] + accG[r];
                float gate = 1.f / (1.f + __expf(-z));
                out[g] = acc[r] * gate + xv[r] * (1.f - gate);
            }
        }
        __syncthreads();   // epilogue LDS reads done before next strip reuses
    }
#undef COMPUTE
}

extern "C" void kernel_launch(void* const* d_in, const int* in_sizes, int n_in,
                              void* d_out, int out_size, void* d_ws, size_t ws_size,
                              hipStream_t stream) {
    const float* x     = (const float*)d_in[0];
    const float* A     = (const float*)d_in[1];
    const float* W_h   = (const float*)d_in[2];
    const float* b_h   = (const float*)d_in[3];
    const float* W_fc1 = (const float*)d_in[4];
    const float* b_fc1 = (const float*)d_in[5];
    const float* W_g1  = (const float*)d_in[6];
    const float* b_g1  = (const float*)d_in[7];
    const float* W_g2  = (const float*)d_in[8];
    const float* b_g2  = (const float*)d_in[9];
    float* out = (float*)d_out;

    char* ws = (char*)d_ws;
    unsigned short* WcT_hi  = (unsigned short*)(ws);            // 32 KB
    unsigned short* WcT_lo  = (unsigned short*)(ws + 32768);    // 32 KB
    unsigned short* Wg1T_hi = (unsigned short*)(ws + 65536);    // 8 KB
    unsigned short* Wg1T_lo = (unsigned short*)(ws + 73728);    // 8 KB
    unsigned short* Wg2T_hi = (unsigned short*)(ws + 81920);    // 8 KB
    unsigned short* Wg2T_lo = (unsigned short*)(ws + 90112);    // 8 KB
    float*          bP1     = (float*)(ws + 98304);             // 256 B
    unsigned short* hF      = (unsigned short*)(ws + 131072);                      // 4 MB
    float*          xprj    = (float*)(ws + 131072 + 4194304);                     // 8 MB
    float*          p1      = (float*)(ws + 131072 + 4194304 + 8388608);           // 8 MB

    prep_k<<<97, 256, 0, stream>>>(W_h, W_fc1, W_g1, W_g2, b_g1, b_g2,
                                   WcT_hi, WcT_lo, Wg1T_hi, Wg1T_lo, Wg2T_hi, Wg2T_lo, bP1);
    k1<<<2048, 64, 0, stream>>>(x, WcT_hi, WcT_lo, Wg1T_hi, Wg1T_lo, b_h, b_fc1, bP1,
                                hF, xprj, p1);
    k2<<<1024, 256, 0, stream>>>(A, hF, Wg2T_hi, Wg2T_lo, p1, xprj, out);
}